// Round 8
// baseline (329.527 us; speedup 1.0000x reference)
//
#include <hip/hip_runtime.h>
#include <hip/hip_bf16.h>

#define B_ 8
#define T_ 4096
#define D_ 1024
#define H_ 1024

typedef __attribute__((ext_vector_type(8))) short short8;
typedef __attribute__((ext_vector_type(4))) float floatx4;

#define GLOAD16(gptr, lptr) \
  __builtin_amdgcn_global_load_lds((const __attribute__((address_space(1))) void*)(gptr), \
                                   (__attribute__((address_space(3))) void*)(lptr), 16, 0, 0)

__device__ __forceinline__ ushort f2b(float f) {
  unsigned x = __builtin_bit_cast(unsigned, f);
  unsigned r = (x + 0x7fffu + ((x >> 16) & 1u)) >> 16;  // RNE, inputs finite
  return (ushort)r;
}
__device__ __forceinline__ float b2f(ushort u) {
  return __builtin_bit_cast(float, (unsigned)u << 16);
}

__global__ void cvt_kernel(const float* __restrict__ in, ushort* __restrict__ out, int n) {
  int idx = blockIdx.x * blockDim.x + threadIdx.x;
  int stride = gridDim.x * blockDim.x;
  for (long i = (long)idx * 8; i < n; i += (long)stride * 8) {
    const float4 f0 = *(const float4*)(in + i);
    const float4 f1 = *(const float4*)(in + i + 4);
    union { ushort u[8]; uint4 v; } r;
    r.u[0] = f2b(f0.x); r.u[1] = f2b(f0.y); r.u[2] = f2b(f0.z); r.u[3] = f2b(f0.w);
    r.u[4] = f2b(f1.x); r.u[5] = f2b(f1.y); r.u[6] = f2b(f1.z); r.u[7] = f2b(f1.w);
    *(uint4*)(out + i) = r.v;
  }
}

__global__ void cvt3_kernel(const float* __restrict__ w0, const float* __restrict__ w1,
                            const float* __restrict__ w2, ushort* __restrict__ out, int n) {
  const float* in = (blockIdx.y == 0) ? w0 : (blockIdx.y == 1) ? w1 : w2;
  ushort* o = out + (size_t)blockIdx.y * n;
  int idx = blockIdx.x * blockDim.x + threadIdx.x;
  int stride = gridDim.x * blockDim.x;
  for (long i = (long)idx * 8; i < n; i += (long)stride * 8) {
    const float4 f0 = *(const float4*)(in + i);
    const float4 f1 = *(const float4*)(in + i + 4);
    union { ushort u[8]; uint4 v; } r;
    r.u[0] = f2b(f0.x); r.u[1] = f2b(f0.y); r.u[2] = f2b(f0.z); r.u[3] = f2b(f0.w);
    r.u[4] = f2b(f1.x); r.u[5] = f2b(f1.y); r.u[6] = f2b(f1.z); r.u[7] = f2b(f1.w);
    *(uint4*)(o + i) = r.v;
  }
}

// ----------------------------------------------------------------------------
// 256x256 B^T GEMM. 8 waves (2wr x 4wc), wave tile 128x64, acc[8][4].
// BK=32, FOUR buffers (A 4x16KB, B 4x16KB = 128 KiB). Per K-tile:
//   issue stage(t+2) -> 12 ds_read_b128 + 32 MFMA (COMPILER-scheduled,
//   counted lgkm interleave, m97-verified) -> vmcnt(4) (t+1 landed; never
//   0 in steady state) -> one raw s_barrier.
// One barrier per 32 MFMA; no forced lgkmcnt(0); LDS reads overlap MFMA.
// WAR safety: buf (t+2)&3 last read at tile t-2, retired before its barrier.
// Swizzle both sides (64B rows, 4 chunks): chunk' = chunk ^ ((row>>1)&3)
// -> 2 lanes/bank (free). Source pre-swizzled, LDS linear for gload_lds.
// Epilogue: in-LDS transpose -> coalesced uint4/float4 stores.
// ----------------------------------------------------------------------------
template <int NCOLS, bool QEPI>
__global__ __launch_bounds__(512, 2) void gemm_bt(
    const ushort* __restrict__ Am, const ushort* __restrict__ Bm,
    ushort* __restrict__ KVout, const float* __restrict__ bq,
    const float* __restrict__ weighted, float* __restrict__ out) {
  extern __shared__ ushort lds[];

  const int tid = threadIdx.x;
  const int lane = tid & 63;
  const int w = tid >> 6;     // 0..7
  const int wr = w >> 2;      // 0..1  (128-row granule)
  const int wc = w & 3;       // 0..3  (64-col granule)
  const int R0 = blockIdx.x * 256;
  const int C0 = blockIdx.y * 256;

  // staging: chunk ci = j*512+tid; row = ci>>2 (= tid>>2 + j*128),
  // phys = ci&3; logical = phys ^ ((row>>1)&3) = (tid&3) ^ ((tid>>3)&3).
  const int r0 = tid >> 2;                       // 0..127
  const int lc = (tid & 3) ^ ((tid >> 3) & 3);
  const ushort* asrc = Am + (size_t)(R0 + r0) * D_ + lc * 8;
  const ushort* bsrc = Bm + (size_t)(C0 + r0) * D_ + lc * 8;

  auto stage = [&](int t) {  // 4 gloads/thread
    const int nb = t & 3;
    const int kt = t * 32;
    GLOAD16(asrc + kt, lds + nb * 8192 + tid * 8);
    GLOAD16(asrc + kt + (size_t)128 * D_, lds + nb * 8192 + (512 + tid) * 8);
    GLOAD16(bsrc + kt, lds + 32768 + nb * 8192 + tid * 8);
    GLOAD16(bsrc + kt + (size_t)128 * D_, lds + 32768 + nb * 8192 + (512 + tid) * 8);
  };

  // fragment reads: row = base + m*16; phys chunk = (lane>>4) ^ ((row>>1)&3)
  // ((row>>1)&3 invariant in m since m*16>>1 = m*8 ≡ 0 mod 4)
  const int baseA = wr * 128 + (lane & 15);
  const int baseB = wc * 64 + (lane & 15);
  const int aOff = baseA * 32 + ((lane >> 4) ^ ((baseA >> 1) & 3)) * 8;
  const int bOff = baseB * 32 + ((lane >> 4) ^ ((baseB >> 1) & 3)) * 8;

  floatx4 acc[8][4] = {};

  stage(0); stage(1);
  asm volatile("s_waitcnt vmcnt(4)" ::: "memory");  // tile 0 landed
  __builtin_amdgcn_s_barrier();

  const int NT = D_ / 32;  // 32
  for (int t = 0; t < NT; ++t) {
    if (t < NT - 2) stage(t + 2);
    const ushort* Ab = lds + (t & 3) * 8192;
    const ushort* Bb = lds + 32768 + (t & 3) * 8192;

    short8 b[4], a[8];
#pragma unroll
    for (int n = 0; n < 4; ++n) b[n] = *(const short8*)(Bb + bOff + n * 512);
#pragma unroll
    for (int m = 0; m < 8; ++m) a[m] = *(const short8*)(Ab + aOff + m * 512);
#pragma unroll
    for (int m = 0; m < 8; ++m)
#pragma unroll
      for (int n = 0; n < 4; ++n)
        acc[m][n] = __builtin_amdgcn_mfma_f32_16x16x32_bf16(a[m], b[n], acc[m][n], 0, 0, 0);

    if (t < NT - 2) { asm volatile("s_waitcnt vmcnt(4)" ::: "memory"); }
    else            { asm volatile("s_waitcnt vmcnt(0)" ::: "memory"); }
    __builtin_amdgcn_s_barrier();
  }

  // ---- epilogue: in-LDS transpose, 2 m-halves, coalesced stores ----
  const int lrb = wr * 64 + (lane >> 4) * 4;  // + mi*16 + r  (0..127)
  const int lcol = wc * 64 + (lane & 15);     // + n*16
#pragma unroll
  for (int mh = 0; mh < 2; ++mh) {
    if (mh) __builtin_amdgcn_s_barrier();
    if constexpr (QEPI) {
      float* lf = (float*)lds;  // 128 x 256 fp32 = 128 KiB
#pragma unroll
      for (int mi = 0; mi < 4; ++mi)
#pragma unroll
        for (int n = 0; n < 4; ++n)
#pragma unroll
          for (int r = 0; r < 4; ++r)
            lf[(lrb + mi * 16 + r) * 256 + lcol + n * 16] = acc[mh * 4 + mi][n][r];
      __builtin_amdgcn_s_barrier();
#pragma unroll
      for (int j = 0; j < 16; ++j) {
        int cidx = j * 512 + tid;    // 0..8191 float4 chunks
        int lr = cidx >> 6;
        int cc = cidx & 63;
        int grow = R0 + (lr >> 6) * 128 + mh * 64 + (lr & 63);
        float4 v = *(float4*)(lf + lr * 256 + cc * 4);
        float4 bq4 = *(const float4*)(bq + C0 + cc * 4);
        float4 wv = *(const float4*)(weighted + (size_t)(grow & (T_ - 1)) * H_ + C0 + cc * 4);
        float4 o;
        o.x = wv.x / (1.f + __expf(-(v.x + bq4.x)));
        o.y = wv.y / (1.f + __expf(-(v.y + bq4.y)));
        o.z = wv.z / (1.f + __expf(-(v.z + bq4.z)));
        o.w = wv.w / (1.f + __expf(-(v.w + bq4.w)));
        *(float4*)(out + (size_t)grow * NCOLS + C0 + cc * 4) = o;
      }
    } else {
      ushort* lh = lds;  // 128 x 256 bf16 = 64 KiB
#pragma unroll
      for (int mi = 0; mi < 4; ++mi)
#pragma unroll
        for (int n = 0; n < 4; ++n)
#pragma unroll
          for (int r = 0; r < 4; ++r)
            lh[(lrb + mi * 16 + r) * 256 + lcol + n * 16] = f2b(acc[mh * 4 + mi][n][r]);
      __builtin_amdgcn_s_barrier();
#pragma unroll
      for (int j = 0; j < 8; ++j) {
        int cidx = j * 512 + tid;    // 0..4095 chunks of 8 bf16
        int lr = cidx >> 5;
        int cc = cidx & 31;
        int grow = R0 + (lr >> 6) * 128 + mh * 64 + (lr & 63);
        uint4 v = *(uint4*)(lh + lr * 256 + cc * 8);
        *(uint4*)(KVout + (size_t)grow * NCOLS + C0 + cc * 8) = v;
      }
    }
  }
}

// Batch reduction: weighted[t,h] = sum_b exp(K+bk+wb)*(V+bv) / sum_b exp(K+bk+wb)
__global__ __launch_bounds__(256) void reduce_kernel(
    const ushort* __restrict__ KV, const float* __restrict__ bk,
    const float* __restrict__ bv, const float* __restrict__ wb,
    float* __restrict__ weighted) {
  const int gid = blockIdx.x * 256 + threadIdx.x;
  const int t = gid >> 7;
  const int h0 = (gid & 127) * 8;

  float bk8[8], bv8[8], wb8[8];
#pragma unroll
  for (int j = 0; j < 8; ++j) {
    bk8[j] = bk[h0 + j];
    bv8[j] = bv[h0 + j];
    wb8[j] = wb[h0 + j];
  }

  float sn[8] = {}, sw[8] = {};
  for (int b = 0; b < B_; ++b) {
    const size_t rowoff = (size_t)(b * T_ + t) * (2 * H_);
    const short8 k8 = *(const short8*)(KV + rowoff + h0);
    const short8 v8 = *(const short8*)(KV + rowoff + H_ + h0);
#pragma unroll
    for (int j = 0; j < 8; ++j) {
      float e = __expf(b2f((ushort)k8[j]) + bk8[j] + wb8[j]);
      sn[j] += e;
      sw[j] += e * (b2f((ushort)v8[j]) + bv8[j]);
    }
  }
  float4 o0, o1;
  o0.x = sw[0] / sn[0]; o0.y = sw[1] / sn[1]; o0.z = sw[2] / sn[2]; o0.w = sw[3] / sn[3];
  o1.x = sw[4] / sn[4]; o1.y = sw[5] / sn[5]; o1.z = sw[6] / sn[6]; o1.w = sw[7] / sn[7];
  *(float4*)(weighted + (size_t)t * H_ + h0) = o0;
  *(float4*)(weighted + (size_t)t * H_ + h0 + 4) = o1;
}

extern "C" void kernel_launch(void* const* d_in, const int* in_sizes, int n_in,
                              void* d_out, int out_size, void* d_ws, size_t ws_size,
                              hipStream_t stream) {
  (void)in_sizes; (void)n_in; (void)out_size; (void)ws_size;
  const float* x = (const float*)d_in[0];
  const float* Wq = (const float*)d_in[1];
  const float* bq = (const float*)d_in[2];
  const float* Wk = (const float*)d_in[3];
  const float* bk = (const float*)d_in[4];
  const float* Wv = (const float*)d_in[5];
  const float* bv = (const float*)d_in[6];
  const float* wbias = (const float*)d_in[7];
  float* out = (float*)d_out;

  char* ws = (char*)d_ws;
  const size_t XN = (size_t)B_ * T_ * D_;   // 33,554,432
  const size_t WN = (size_t)H_ * D_;        // 1,048,576
  ushort* xb   = (ushort*)ws;                            // 64 MiB
  ushort* Wqb  = (ushort*)(ws + XN * 2);                 // 2 MiB
  ushort* Wkvb = Wqb + WN;                               // 4 MiB (Wk|Wv contiguous)
  float* weighted = (float*)(ws + XN * 2 + 3 * WN * 2);  // 16 MiB
  ushort* KV = (ushort*)(ws + XN * 2 + 3 * WN * 2 + (size_t)T_ * H_ * 4);  // 128 MiB

  (void)hipFuncSetAttribute((const void*)gemm_bt<2048, false>,
                            hipFuncAttributeMaxDynamicSharedMemorySize, 131072);
  (void)hipFuncSetAttribute((const void*)gemm_bt<1024, true>,
                            hipFuncAttributeMaxDynamicSharedMemorySize, 131072);

  cvt_kernel<<<2048, 256, 0, stream>>>(x, xb, (int)XN);
  cvt3_kernel<<<dim3(512, 3), 256, 0, stream>>>(Wq, Wk, Wv, Wqb, (int)WN);

  gemm_bt<2048, false><<<dim3((B_ * T_) / 256, 2048 / 256), 512, 131072, stream>>>(
      xb, Wkvb, KV, nullptr, nullptr, nullptr);
  reduce_kernel<<<(T_ * H_ / 8) / 256, 256, 0, stream>>>(KV, bk, bv, wbias, weighted);
  gemm_bt<1024, true><<<dim3((B_ * T_) / 256, 1024 / 256), 512, 131072, stream>>>(
      xb, Wqb, nullptr, bq, weighted, out);
}

// Round 9
// 324.812 us; speedup vs baseline: 1.0145x; 1.0145x over previous
//
#include <hip/hip_runtime.h>
#include <hip/hip_bf16.h>

#define B_ 8
#define T_ 4096
#define D_ 1024
#define H_ 1024

typedef __attribute__((ext_vector_type(8))) short short8;
typedef __attribute__((ext_vector_type(4))) float floatx4;

#define GLOAD16(gptr, lptr) \
  __builtin_amdgcn_global_load_lds((const __attribute__((address_space(1))) void*)(gptr), \
                                   (__attribute__((address_space(3))) void*)(lptr), 16, 0, 0)

__device__ __forceinline__ ushort f2b(float f) {
  unsigned x = __builtin_bit_cast(unsigned, f);
  unsigned r = (x + 0x7fffu + ((x >> 16) & 1u)) >> 16;  // RNE, inputs finite
  return (ushort)r;
}
__device__ __forceinline__ float b2f(ushort u) {
  return __builtin_bit_cast(float, (unsigned)u << 16);
}

__global__ void cvt_kernel(const float* __restrict__ in, ushort* __restrict__ out, int n) {
  int idx = blockIdx.x * blockDim.x + threadIdx.x;
  int stride = gridDim.x * blockDim.x;
  for (long i = (long)idx * 8; i < n; i += (long)stride * 8) {
    const float4 f0 = *(const float4*)(in + i);
    const float4 f1 = *(const float4*)(in + i + 4);
    union { ushort u[8]; uint4 v; } r;
    r.u[0] = f2b(f0.x); r.u[1] = f2b(f0.y); r.u[2] = f2b(f0.z); r.u[3] = f2b(f0.w);
    r.u[4] = f2b(f1.x); r.u[5] = f2b(f1.y); r.u[6] = f2b(f1.z); r.u[7] = f2b(f1.w);
    *(uint4*)(out + i) = r.v;
  }
}

__global__ void cvt3_kernel(const float* __restrict__ w0, const float* __restrict__ w1,
                            const float* __restrict__ w2, ushort* __restrict__ out, int n) {
  const float* in = (blockIdx.y == 0) ? w0 : (blockIdx.y == 1) ? w1 : w2;
  ushort* o = out + (size_t)blockIdx.y * n;
  int idx = blockIdx.x * blockDim.x + threadIdx.x;
  int stride = gridDim.x * blockDim.x;
  for (long i = (long)idx * 8; i < n; i += (long)stride * 8) {
    const float4 f0 = *(const float4*)(in + i);
    const float4 f1 = *(const float4*)(in + i + 4);
    union { ushort u[8]; uint4 v; } r;
    r.u[0] = f2b(f0.x); r.u[1] = f2b(f0.y); r.u[2] = f2b(f0.z); r.u[3] = f2b(f0.w);
    r.u[4] = f2b(f1.x); r.u[5] = f2b(f1.y); r.u[6] = f2b(f1.z); r.u[7] = f2b(f1.w);
    *(uint4*)(o + i) = r.v;
  }
}

// ----------------------------------------------------------------------------
// 256x256 B^T GEMM. 8 waves (2wr x 4wc), wave tile 128x64, acc[8][4].
// BK=32, FOUR buffers (128 KiB). REGISTER PING-PONG: tile t+1's B[4] and
// A[m0-3] fragments are ds_read during tile t's MFMA window (no same-iter
// consumer -> compiler defers waits); only A[m4-7] (aS) is read same-iter,
// consumed by the second MFMA cluster (hides under the first 16 MFMAs).
// At barrier release MFMAs issue immediately from registers -> LDS pipe
// drains concurrently with matrix pipe instead of serially (R8 lesson).
// Stage runway: iter t stages t+3; vmcnt(4) per iter guarantees buf t+2
// landed at iter t's end (read next iter). WAR: buf (t+3)&3 last read in
// iter t-2, retired before end-of-(t-1) barrier.
// Swizzle both sides (64B rows, 4 chunks): chunk' = chunk ^ ((row>>1)&3).
// Epilogue: in-LDS transpose -> coalesced uint4/float4 stores.
// ----------------------------------------------------------------------------
template <int NCOLS, bool QEPI>
__global__ __launch_bounds__(512, 2) void gemm_bt(
    const ushort* __restrict__ Am, const ushort* __restrict__ Bm,
    ushort* __restrict__ KVout, const float* __restrict__ bq,
    const float* __restrict__ weighted, float* __restrict__ out) {
  extern __shared__ ushort lds[];

  const int tid = threadIdx.x;
  const int lane = tid & 63;
  const int w = tid >> 6;     // 0..7
  const int wr = w >> 2;      // 0..1  (128-row granule)
  const int wc = w & 3;       // 0..3  (64-col granule)
  const int R0 = blockIdx.x * 256;
  const int C0 = blockIdx.y * 256;

  // staging: chunk ci = j*512+tid; row = ci>>2, phys = ci&3;
  // source logical chunk = phys ^ ((row>>1)&3) = (tid&3) ^ ((tid>>3)&3).
  const int r0 = tid >> 2;                       // 0..127
  const int lc = (tid & 3) ^ ((tid >> 3) & 3);
  const ushort* asrc = Am + (size_t)(R0 + r0) * D_ + lc * 8;
  const ushort* bsrc = Bm + (size_t)(C0 + r0) * D_ + lc * 8;

  auto stage = [&](int t) {  // 4 gloads/thread
    const int nb = t & 3;
    const int kt = t * 32;
    GLOAD16(asrc + kt, lds + nb * 8192 + tid * 8);
    GLOAD16(asrc + kt + (size_t)128 * D_, lds + nb * 8192 + (512 + tid) * 8);
    GLOAD16(bsrc + kt, lds + 32768 + nb * 8192 + tid * 8);
    GLOAD16(bsrc + kt + (size_t)128 * D_, lds + 32768 + nb * 8192 + (512 + tid) * 8);
  };

  // fragment reads: row = base + m*16; phys chunk = (lane>>4) ^ ((row>>1)&3)
  const int baseA = wr * 128 + (lane & 15);
  const int baseB = wc * 64 + (lane & 15);
  const int aOff = baseA * 32 + ((lane >> 4) ^ ((baseA >> 1) & 3)) * 8;
  const int bOff = baseB * 32 + ((lane >> 4) ^ ((baseB >> 1) & 3)) * 8;

  floatx4 acc[8][4] = {};
  short8 aP[4], aN[4], aS[4], bP[4], bN[4];

  auto ldB = [&](short8* d, int tt) {
    const ushort* Bb = lds + 32768 + (tt & 3) * 8192;
#pragma unroll
    for (int n = 0; n < 4; ++n) d[n] = *(const short8*)(Bb + bOff + n * 512);
  };
  auto ldA = [&](short8* d, int tt, int mo) {
    const ushort* Ab = lds + (tt & 3) * 8192;
#pragma unroll
    for (int m = 0; m < 4; ++m) d[m] = *(const short8*)(Ab + aOff + (mo + m) * 512);
  };
  auto mm = [&](const short8* a4, const short8* b4, int mo) {
#pragma unroll
    for (int m = 0; m < 4; ++m)
#pragma unroll
      for (int n = 0; n < 4; ++n)
        acc[mo + m][n] =
            __builtin_amdgcn_mfma_f32_16x16x32_bf16(a4[m], b4[n], acc[mo + m][n], 0, 0, 0);
  };

  stage(0); stage(1); stage(2);
  asm volatile("s_waitcnt vmcnt(4)" ::: "memory");  // bufs 0,1 landed
  __builtin_amdgcn_s_barrier();
  ldB(bP, 0); ldA(aP, 0, 0);

  const int NT = D_ / 32;  // 32
  for (int t = 0; t < NT; t += 2) {
    // ---- sub-iter t: compute tile t; prefetch frags of t+1 ----
    if (t + 3 < NT) stage(t + 3);
    ldA(aS, t, 4);              // same-iter: feeds 2nd MFMA cluster
    ldB(bN, t + 1);             // next-iter frags
    ldA(aN, t + 1, 0);
    __builtin_amdgcn_s_setprio(1);
    mm(aP, bP, 0);
    mm(aS, bP, 4);
    __builtin_amdgcn_s_setprio(0);
    if (t < NT - 3) { asm volatile("s_waitcnt vmcnt(4)" ::: "memory"); }
    else            { asm volatile("s_waitcnt vmcnt(0)" ::: "memory"); }
    __builtin_amdgcn_s_barrier();

    // ---- sub-iter t+1: compute tile t+1; prefetch frags of t+2 ----
    if (t + 4 < NT) stage(t + 4);
    ldA(aS, t + 1, 4);
    if (t + 2 < NT) { ldB(bP, t + 2); ldA(aP, t + 2, 0); }
    __builtin_amdgcn_s_setprio(1);
    mm(aN, bN, 0);
    mm(aS, bN, 4);
    __builtin_amdgcn_s_setprio(0);
    if (t + 1 < NT - 3) { asm volatile("s_waitcnt vmcnt(4)" ::: "memory"); }
    else                { asm volatile("s_waitcnt vmcnt(0)" ::: "memory"); }
    __builtin_amdgcn_s_barrier();
  }

  // ---- epilogue: in-LDS transpose, 2 m-halves, coalesced stores ----
  const int lrb = wr * 64 + (lane >> 4) * 4;  // + mi*16 + r  (0..127)
  const int lcol = wc * 64 + (lane & 15);     // + n*16
#pragma unroll
  for (int mh = 0; mh < 2; ++mh) {
    if (mh) __builtin_amdgcn_s_barrier();
    if constexpr (QEPI) {
      float* lf = (float*)lds;  // 128 x 256 fp32 = 128 KiB
#pragma unroll
      for (int mi = 0; mi < 4; ++mi)
#pragma unroll
        for (int n = 0; n < 4; ++n)
#pragma unroll
          for (int r = 0; r < 4; ++r)
            lf[(lrb + mi * 16 + r) * 256 + lcol + n * 16] = acc[mh * 4 + mi][n][r];
      __builtin_amdgcn_s_barrier();
#pragma unroll
      for (int j = 0; j < 16; ++j) {
        int cidx = j * 512 + tid;    // 0..8191 float4 chunks
        int lr = cidx >> 6;
        int cc = cidx & 63;
        int grow = R0 + (lr >> 6) * 128 + mh * 64 + (lr & 63);
        float4 v = *(float4*)(lf + lr * 256 + cc * 4);
        float4 bq4 = *(const float4*)(bq + C0 + cc * 4);
        float4 wv = *(const float4*)(weighted + (size_t)(grow & (T_ - 1)) * H_ + C0 + cc * 4);
        float4 o;
        o.x = wv.x / (1.f + __expf(-(v.x + bq4.x)));
        o.y = wv.y / (1.f + __expf(-(v.y + bq4.y)));
        o.z = wv.z / (1.f + __expf(-(v.z + bq4.z)));
        o.w = wv.w / (1.f + __expf(-(v.w + bq4.w)));
        *(float4*)(out + (size_t)grow * NCOLS + C0 + cc * 4) = o;
      }
    } else {
      ushort* lh = lds;  // 128 x 256 bf16 = 64 KiB
#pragma unroll
      for (int mi = 0; mi < 4; ++mi)
#pragma unroll
        for (int n = 0; n < 4; ++n)
#pragma unroll
          for (int r = 0; r < 4; ++r)
            lh[(lrb + mi * 16 + r) * 256 + lcol + n * 16] = f2b(acc[mh * 4 + mi][n][r]);
      __builtin_amdgcn_s_barrier();
#pragma unroll
      for (int j = 0; j < 8; ++j) {
        int cidx = j * 512 + tid;    // 0..4095 chunks of 8 bf16
        int lr = cidx >> 5;
        int cc = cidx & 31;
        int grow = R0 + (lr >> 6) * 128 + mh * 64 + (lr & 63);
        uint4 v = *(uint4*)(lh + lr * 256 + cc * 8);
        *(uint4*)(KVout + (size_t)grow * NCOLS + C0 + cc * 8) = v;
      }
    }
  }
}

// Batch reduction: weighted[t,h] = sum_b exp(K+bk+wb)*(V+bv) / sum_b exp(K+bk+wb)
__global__ __launch_bounds__(256) void reduce_kernel(
    const ushort* __restrict__ KV, const float* __restrict__ bk,
    const float* __restrict__ bv, const float* __restrict__ wb,
    float* __restrict__ weighted) {
  const int gid = blockIdx.x * 256 + threadIdx.x;
  const int t = gid >> 7;
  const int h0 = (gid & 127) * 8;

  float bk8[8], bv8[8], wb8[8];
#pragma unroll
  for (int j = 0; j < 8; ++j) {
    bk8[j] = bk[h0 + j];
    bv8[j] = bv[h0 + j];
    wb8[j] = wb[h0 + j];
  }

  float sn[8] = {}, sw[8] = {};
  for (int b = 0; b < B_; ++b) {
    const size_t rowoff = (size_t)(b * T_ + t) * (2 * H_);
    const short8 k8 = *(const short8*)(KV + rowoff + h0);
    const short8 v8 = *(const short8*)(KV + rowoff + H_ + h0);
#pragma unroll
    for (int j = 0; j < 8; ++j) {
      float e = __expf(b2f((ushort)k8[j]) + bk8[j] + wb8[j]);
      sn[j] += e;
      sw[j] += e * (b2f((ushort)v8[j]) + bv8[j]);
    }
  }
  float4 o0, o1;
  o0.x = sw[0] / sn[0]; o0.y = sw[1] / sn[1]; o0.z = sw[2] / sn[2]; o0.w = sw[3] / sn[3];
  o1.x = sw[4] / sn[4]; o1.y = sw[5] / sn[5]; o1.z = sw[6] / sn[6]; o1.w = sw[7] / sn[7];
  *(float4*)(weighted + (size_t)t * H_ + h0) = o0;
  *(float4*)(weighted + (size_t)t * H_ + h0 + 4) = o1;
}

extern "C" void kernel_launch(void* const* d_in, const int* in_sizes, int n_in,
                              void* d_out, int out_size, void* d_ws, size_t ws_size,
                              hipStream_t stream) {
  (void)in_sizes; (void)n_in; (void)out_size; (void)ws_size;
  const float* x = (const float*)d_in[0];
  const float* Wq = (const float*)d_in[1];
  const float* bq = (const float*)d_in[2];
  const float* Wk = (const float*)d_in[3];
  const float* bk = (const float*)d_in[4];
  const float* Wv = (const float*)d_in[5];
  const float* bv = (const float*)d_in[6];
  const float* wbias = (const float*)d_in[7];
  float* out = (float*)d_out;

  char* ws = (char*)d_ws;
  const size_t XN = (size_t)B_ * T_ * D_;   // 33,554,432
  const size_t WN = (size_t)H_ * D_;        // 1,048,576
  ushort* xb   = (ushort*)ws;                            // 64 MiB
  ushort* Wqb  = (ushort*)(ws + XN * 2);                 // 2 MiB
  ushort* Wkvb = Wqb + WN;                               // 4 MiB (Wk|Wv contiguous)
  float* weighted = (float*)(ws + XN * 2 + 3 * WN * 2);  // 16 MiB
  ushort* KV = (ushort*)(ws + XN * 2 + 3 * WN * 2 + (size_t)T_ * H_ * 4);  // 128 MiB

  (void)hipFuncSetAttribute((const void*)gemm_bt<2048, false>,
                            hipFuncAttributeMaxDynamicSharedMemorySize, 131072);
  (void)hipFuncSetAttribute((const void*)gemm_bt<1024, true>,
                            hipFuncAttributeMaxDynamicSharedMemorySize, 131072);

  cvt_kernel<<<2048, 256, 0, stream>>>(x, xb, (int)XN);
  cvt3_kernel<<<dim3(512, 3), 256, 0, stream>>>(Wq, Wk, Wv, Wqb, (int)WN);

  gemm_bt<2048, false><<<dim3((B_ * T_) / 256, 2048 / 256), 512, 131072, stream>>>(
      xb, Wkvb, KV, nullptr, nullptr, nullptr);
  reduce_kernel<<<(T_ * H_ / 8) / 256, 256, 0, stream>>>(KV, bk, bv, wbias, weighted);
  gemm_bt<1024, true><<<dim3((B_ * T_) / 256, 1024 / 256), 512, 131072, stream>>>(
      xb, Wqb, nullptr, bq, weighted, out);
}

// Round 10
// 276.859 us; speedup vs baseline: 1.1902x; 1.1732x over previous
//
#include <hip/hip_runtime.h>
#include <hip/hip_bf16.h>

#define B_ 8
#define T_ 4096
#define D_ 1024
#define H_ 1024

typedef __attribute__((ext_vector_type(8))) short short8;
typedef __attribute__((ext_vector_type(4))) float floatx4;

#define GLOAD16(gptr, lptr) \
  __builtin_amdgcn_global_load_lds((const __attribute__((address_space(1))) void*)(gptr), \
                                   (__attribute__((address_space(3))) void*)(lptr), 16, 0, 0)

__device__ __forceinline__ ushort f2b(float f) {
  unsigned x = __builtin_bit_cast(unsigned, f);
  unsigned r = (x + 0x7fffu + ((x >> 16) & 1u)) >> 16;  // RNE, inputs finite
  return (ushort)r;
}

__global__ void cvt_kernel(const float* __restrict__ in, ushort* __restrict__ out, int n) {
  int idx = blockIdx.x * blockDim.x + threadIdx.x;
  int stride = gridDim.x * blockDim.x;
  for (long i = (long)idx * 8; i < n; i += (long)stride * 8) {
    const float4 f0 = *(const float4*)(in + i);
    const float4 f1 = *(const float4*)(in + i + 4);
    union { ushort u[8]; uint4 v; } r;
    r.u[0] = f2b(f0.x); r.u[1] = f2b(f0.y); r.u[2] = f2b(f0.z); r.u[3] = f2b(f0.w);
    r.u[4] = f2b(f1.x); r.u[5] = f2b(f1.y); r.u[6] = f2b(f1.z); r.u[7] = f2b(f1.w);
    *(uint4*)(out + i) = r.v;
  }
}

__global__ void cvt3_kernel(const float* __restrict__ w0, const float* __restrict__ w1,
                            const float* __restrict__ w2, ushort* __restrict__ out, int n) {
  const float* in = (blockIdx.y == 0) ? w0 : (blockIdx.y == 1) ? w1 : w2;
  ushort* o = out + (size_t)blockIdx.y * n;
  int idx = blockIdx.x * blockDim.x + threadIdx.x;
  int stride = gridDim.x * blockDim.x;
  for (long i = (long)idx * 8; i < n; i += (long)stride * 8) {
    const float4 f0 = *(const float4*)(in + i);
    const float4 f1 = *(const float4*)(in + i + 4);
    union { ushort u[8]; uint4 v; } r;
    r.u[0] = f2b(f0.x); r.u[1] = f2b(f0.y); r.u[2] = f2b(f0.z); r.u[3] = f2b(f0.w);
    r.u[4] = f2b(f1.x); r.u[5] = f2b(f1.y); r.u[6] = f2b(f1.z); r.u[7] = f2b(f1.w);
    *(uint4*)(o + i) = r.v;
  }
}

// K1: fused K/V GEMM + batch reduction (R4 structure, passed @149.6us).
// Block 256t x 64h, 8 waves (4t x 2h), wave tile 64t x 32h (m4 n2).
// Triple-buffered LDS (144 KiB), counted vmcnt(6), 1 raw barrier/phase.
// NEW: 1-D grid + XCD swizzle: lid=(bid&7)*32+(bid>>3); XCD x owns t-panels
// [2x,2x+2) with all 16 h-panels adjacent -> per-XCD working set ~1 MB/b-step
// (L2-resident), xb fetched ~once from HBM.
__global__ __launch_bounds__(512, 2) void kv_kernel(
    const ushort* __restrict__ xb, const ushort* __restrict__ Wkb,
    const ushort* __restrict__ Wvb, const float* __restrict__ bk,
    const float* __restrict__ bv, const float* __restrict__ wbias,
    float* __restrict__ weighted) {
  extern __shared__ ushort lds[];
  ushort* const AsB = lds;              // 3 bufs x 256x64 = 3x16384 elems
  ushort* const KsB = lds + 49152;      // 3 bufs x 64x64  = 3x4096
  ushort* const VsB = lds + 61440;      // 3 bufs x 64x64  = 3x4096

  const int tid = threadIdx.x;
  const int lane = tid & 63;
  const int w = tid >> 6;       // 0..7
  const int wrow = w >> 1;      // 0..3  (64-row granule)
  const int wcol = w & 1;       // 0..1  (32-col granule)

  const int bid = blockIdx.x;               // 256 blocks
  const int lid = (bid & 7) * 32 + (bid >> 3);
  const int t0 = (lid >> 4) * 256;          // t-panel 0..15
  const int h0 = (lid & 15) * 64;           // h-panel 0..15

  const int srow = tid >> 3;                     // 0..63
  const int swz = (tid & 7) ^ ((tid >> 3) & 7);  // source chunk (const/thread)

  const int arow = wrow * 64 + (lane & 15);
  const int bcol = wcol * 32 + (lane & 15);
  const int cs0 = (lane >> 4) ^ (lane & 7);        // k-sub 0 phys chunk
  const int cs1 = ((lane >> 4) + 4) ^ (lane & 7);  // k-sub 1

  float wbc[2], bkc[2], bvc[2];
#pragma unroll
  for (int n = 0; n < 2; ++n) {
    int h = h0 + wcol * 32 + n * 16 + (lane & 15);
    wbc[n] = wbias[h];
    bkc[n] = bk[h];
    bvc[n] = bv[h];
  }

  const ushort* xsb = xb + (size_t)(t0 + srow) * D_ + swz * 8;
  const ushort* ksb = Wkb + (size_t)(h0 + srow) * D_ + swz * 8;
  const ushort* vsb = Wvb + (size_t)(h0 + srow) * D_ + swz * 8;

  auto stage = [&](int p, int nb) {  // 6 loads/thread
    const int b = p >> 4;
    const int kt = (p & 15) << 6;
    const ushort* xs = xsb + (size_t)b * (T_ * D_) + kt;
    ushort* Ab = AsB + nb * 16384;
#pragma unroll
    for (int it = 0; it < 4; ++it)
      GLOAD16(xs + (size_t)(it * 64) * D_, Ab + (it * 512 + tid) * 8);
    GLOAD16(ksb + kt, KsB + nb * 4096 + tid * 8);
    GLOAD16(vsb + kt, VsB + nb * 4096 + tid * 8);
  };

  floatx4 accK[4][2] = {};
  floatx4 accV[4][2] = {};
  floatx4 sumN[4][2] = {};
  floatx4 sumWV[4][2] = {};

  stage(0, 0);
  stage(1, 1);
  asm volatile("s_waitcnt vmcnt(6)" ::: "memory");  // stage(0) landed
  __builtin_amdgcn_s_barrier();

  int cur = 0, stg = 2;
  for (int p = 0; p < 128; ++p) {
    if (p < 126) stage(p + 2, stg);

    const ushort* Ac = AsB + cur * 16384;
    const ushort* Kc = KsB + cur * 4096;
    const ushort* Vc = VsB + cur * 4096;
#pragma unroll
    for (int s = 0; s < 2; ++s) {
      const int cs = s ? cs1 : cs0;
      short8 a[4], kb2[2], vb2[2];
#pragma unroll
      for (int m = 0; m < 4; ++m)
        a[m] = *(const short8*)&Ac[(arow + m * 16) * 64 + cs * 8];
#pragma unroll
      for (int n = 0; n < 2; ++n) {
        kb2[n] = *(const short8*)&Kc[(bcol + n * 16) * 64 + cs * 8];
        vb2[n] = *(const short8*)&Vc[(bcol + n * 16) * 64 + cs * 8];
      }
      __builtin_amdgcn_s_setprio(1);
#pragma unroll
      for (int m = 0; m < 4; ++m)
#pragma unroll
        for (int n = 0; n < 2; ++n) {
          accK[m][n] = __builtin_amdgcn_mfma_f32_16x16x32_bf16(a[m], kb2[n], accK[m][n], 0, 0, 0);
          accV[m][n] = __builtin_amdgcn_mfma_f32_16x16x32_bf16(a[m], vb2[n], accV[m][n], 0, 0, 0);
        }
      __builtin_amdgcn_s_setprio(0);
    }

    if ((p & 15) == 15) {  // end of batch: fold into exp-weighted sums
#pragma unroll
      for (int m = 0; m < 4; ++m)
#pragma unroll
        for (int n = 0; n < 2; ++n) {
#pragma unroll
          for (int r = 0; r < 4; ++r) {
            float nmr = __expf(accK[m][n][r] + bkc[n] + wbc[n]);
            sumN[m][n][r] += nmr;
            sumWV[m][n][r] += nmr * (accV[m][n][r] + bvc[n]);
          }
          accK[m][n] = floatx4{0.f, 0.f, 0.f, 0.f};
          accV[m][n] = floatx4{0.f, 0.f, 0.f, 0.f};
        }
    }

    if (p < 126) { asm volatile("s_waitcnt vmcnt(6)" ::: "memory"); }
    else         { asm volatile("s_waitcnt vmcnt(0)" ::: "memory"); }
    __builtin_amdgcn_s_barrier();
    cur = (cur == 2) ? 0 : cur + 1;
    stg = (stg == 2) ? 0 : stg + 1;
  }

  // C/D layout: col = lane&15, row = (lane>>4)*4 + r
#pragma unroll
  for (int m = 0; m < 4; ++m)
#pragma unroll
    for (int n = 0; n < 2; ++n)
#pragma unroll
      for (int r = 0; r < 4; ++r) {
        int t = t0 + wrow * 64 + m * 16 + (lane >> 4) * 4 + r;
        int h = h0 + wcol * 32 + n * 16 + (lane & 15);
        weighted[(size_t)t * H_ + h] = sumWV[m][n][r] / sumN[m][n][r];
      }
}

// K2: Q GEMM + sigmoid(Q)*weighted epilogue (R8 structure, passed).
// 256r x 256c tile over B*T x H; BK=32, 4 buffers, counted vmcnt(4),
// 1 barrier per tile, compiler-scheduled lgkm interleave.
// NEW: 1-D grid + XCD swizzle: lid=(bid&7)*64+(bid>>3); XCD x owns row-panels
// [16x,16x+16) with all 4 col-panels adjacent -> xb slice L2-resident.
__global__ __launch_bounds__(512, 2) void q_kernel(
    const ushort* __restrict__ Am, const ushort* __restrict__ Bm,
    const float* __restrict__ bq, const float* __restrict__ weighted,
    float* __restrict__ out) {
  extern __shared__ ushort lds[];

  const int tid = threadIdx.x;
  const int lane = tid & 63;
  const int w = tid >> 6;     // 0..7
  const int wr = w >> 2;      // 0..1  (128-row granule)
  const int wc = w & 3;       // 0..3  (64-col granule)

  const int bid = blockIdx.x;               // 512 blocks
  const int lid = (bid & 7) * 64 + (bid >> 3);
  const int R0 = (lid >> 2) * 256;          // row-panel 0..127
  const int C0 = (lid & 3) * 256;           // col-panel 0..3

  // staging: chunk ci = j*512+tid; row = ci>>2, phys = ci&3;
  // source logical chunk = phys ^ ((row>>1)&3) = (tid&3) ^ ((tid>>3)&3).
  const int r0 = tid >> 2;                       // 0..127
  const int lc = (tid & 3) ^ ((tid >> 3) & 3);
  const ushort* asrc = Am + (size_t)(R0 + r0) * D_ + lc * 8;
  const ushort* bsrc = Bm + (size_t)(C0 + r0) * D_ + lc * 8;

  auto stage = [&](int t) {  // 4 gloads/thread
    const int nb = t & 3;
    const int kt = t * 32;
    GLOAD16(asrc + kt, lds + nb * 8192 + tid * 8);
    GLOAD16(asrc + kt + (size_t)128 * D_, lds + nb * 8192 + (512 + tid) * 8);
    GLOAD16(bsrc + kt, lds + 32768 + nb * 8192 + tid * 8);
    GLOAD16(bsrc + kt + (size_t)128 * D_, lds + 32768 + nb * 8192 + (512 + tid) * 8);
  };

  // fragment reads: row = base + m*16; phys chunk = (lane>>4) ^ ((row>>1)&3)
  const int baseA = wr * 128 + (lane & 15);
  const int baseB = wc * 64 + (lane & 15);
  const int aOff = baseA * 32 + ((lane >> 4) ^ ((baseA >> 1) & 3)) * 8;
  const int bOff = baseB * 32 + ((lane >> 4) ^ ((baseB >> 1) & 3)) * 8;

  floatx4 acc[8][4] = {};

  stage(0); stage(1);
  asm volatile("s_waitcnt vmcnt(4)" ::: "memory");  // tile 0 landed
  __builtin_amdgcn_s_barrier();

  const int NT = D_ / 32;  // 32
  for (int t = 0; t < NT; ++t) {
    if (t < NT - 2) stage(t + 2);
    const ushort* Ab = lds + (t & 3) * 8192;
    const ushort* Bb = lds + 32768 + (t & 3) * 8192;

    short8 b[4], a[8];
#pragma unroll
    for (int n = 0; n < 4; ++n) b[n] = *(const short8*)(Bb + bOff + n * 512);
#pragma unroll
    for (int m = 0; m < 8; ++m) a[m] = *(const short8*)(Ab + aOff + m * 512);
#pragma unroll
    for (int m = 0; m < 8; ++m)
#pragma unroll
      for (int n = 0; n < 4; ++n)
        acc[m][n] = __builtin_amdgcn_mfma_f32_16x16x32_bf16(a[m], b[n], acc[m][n], 0, 0, 0);

    if (t < NT - 2) { asm volatile("s_waitcnt vmcnt(4)" ::: "memory"); }
    else            { asm volatile("s_waitcnt vmcnt(0)" ::: "memory"); }
    __builtin_amdgcn_s_barrier();
  }

  // ---- epilogue: in-LDS transpose, 2 m-halves, coalesced stores ----
  const int lrb = wr * 64 + (lane >> 4) * 4;  // + mi*16 + r  (0..127)
  const int lcol = wc * 64 + (lane & 15);     // + n*16
#pragma unroll
  for (int mh = 0; mh < 2; ++mh) {
    if (mh) __builtin_amdgcn_s_barrier();
    float* lf = (float*)lds;  // 128 x 256 fp32 = 128 KiB
#pragma unroll
    for (int mi = 0; mi < 4; ++mi)
#pragma unroll
      for (int n = 0; n < 4; ++n)
#pragma unroll
        for (int r = 0; r < 4; ++r)
          lf[(lrb + mi * 16 + r) * 256 + lcol + n * 16] = acc[mh * 4 + mi][n][r];
    __builtin_amdgcn_s_barrier();
#pragma unroll
    for (int j = 0; j < 16; ++j) {
      int cidx = j * 512 + tid;    // 0..8191 float4 chunks
      int lr = cidx >> 6;
      int cc = cidx & 63;
      int grow = R0 + (lr >> 6) * 128 + mh * 64 + (lr & 63);
      float4 v = *(float4*)(lf + lr * 256 + cc * 4);
      float4 bq4 = *(const float4*)(bq + C0 + cc * 4);
      float4 wv = *(const float4*)(weighted + (size_t)(grow & (T_ - 1)) * H_ + C0 + cc * 4);
      float4 o;
      o.x = wv.x / (1.f + __expf(-(v.x + bq4.x)));
      o.y = wv.y / (1.f + __expf(-(v.y + bq4.y)));
      o.z = wv.z / (1.f + __expf(-(v.z + bq4.z)));
      o.w = wv.w / (1.f + __expf(-(v.w + bq4.w)));
      *(float4*)(out + (size_t)grow * H_ + C0 + cc * 4) = o;
    }
  }
}

extern "C" void kernel_launch(void* const* d_in, const int* in_sizes, int n_in,
                              void* d_out, int out_size, void* d_ws, size_t ws_size,
                              hipStream_t stream) {
  (void)in_sizes; (void)n_in; (void)out_size; (void)ws_size;
  const float* x = (const float*)d_in[0];
  const float* Wq = (const float*)d_in[1];
  const float* bq = (const float*)d_in[2];
  const float* Wk = (const float*)d_in[3];
  const float* bk = (const float*)d_in[4];
  const float* Wv = (const float*)d_in[5];
  const float* bv = (const float*)d_in[6];
  const float* wbias = (const float*)d_in[7];
  float* out = (float*)d_out;

  char* ws = (char*)d_ws;
  const size_t XN = (size_t)B_ * T_ * D_;   // 33,554,432
  const size_t WN = (size_t)H_ * D_;        // 1,048,576
  ushort* xb  = (ushort*)ws;                             // 64 MiB
  ushort* Wqb = (ushort*)(ws + XN * 2);                  // 2 MiB
  ushort* Wkb = Wqb + WN;                                // 2 MiB
  ushort* Wvb = Wkb + WN;                                // 2 MiB
  float* weighted = (float*)(ws + XN * 2 + 3 * WN * 2);  // 16 MiB

  (void)hipFuncSetAttribute((const void*)kv_kernel,
                            hipFuncAttributeMaxDynamicSharedMemorySize, 147456);
  (void)hipFuncSetAttribute((const void*)q_kernel,
                            hipFuncAttributeMaxDynamicSharedMemorySize, 131072);

  cvt_kernel<<<2048, 256, 0, stream>>>(x, xb, (int)XN);
  cvt3_kernel<<<dim3(512, 3), 256, 0, stream>>>(Wq, Wk, Wv, Wqb, (int)WN);

  kv_kernel<<<256, 512, 147456, stream>>>(xb, Wkb, Wvb, bk, bv, wbias, weighted);
  q_kernel<<<512, 512, 131072, stream>>>(xb, Wqb, bq, weighted, out);
}

// Round 11
// 275.340 us; speedup vs baseline: 1.1968x; 1.0055x over previous
//
#include <hip/hip_runtime.h>
#include <hip/hip_bf16.h>

#define B_ 8
#define T_ 4096
#define D_ 1024
#define H_ 1024

typedef __attribute__((ext_vector_type(8))) short short8;
typedef __attribute__((ext_vector_type(4))) float floatx4;

#define GLOAD16(gptr, lptr) \
  __builtin_amdgcn_global_load_lds((const __attribute__((address_space(1))) void*)(gptr), \
                                   (__attribute__((address_space(3))) void*)(lptr), 16, 0, 0)

__device__ __forceinline__ ushort f2b(float f) {
  unsigned x = __builtin_bit_cast(unsigned, f);
  unsigned r = (x + 0x7fffu + ((x >> 16) & 1u)) >> 16;  // RNE, inputs finite
  return (ushort)r;
}

__global__ void cvt_kernel(const float* __restrict__ in, ushort* __restrict__ out, int n) {
  int idx = blockIdx.x * blockDim.x + threadIdx.x;
  int stride = gridDim.x * blockDim.x;
  for (long i = (long)idx * 8; i < n; i += (long)stride * 8) {
    const float4 f0 = *(const float4*)(in + i);
    const float4 f1 = *(const float4*)(in + i + 4);
    union { ushort u[8]; uint4 v; } r;
    r.u[0] = f2b(f0.x); r.u[1] = f2b(f0.y); r.u[2] = f2b(f0.z); r.u[3] = f2b(f0.w);
    r.u[4] = f2b(f1.x); r.u[5] = f2b(f1.y); r.u[6] = f2b(f1.z); r.u[7] = f2b(f1.w);
    *(uint4*)(out + i) = r.v;
  }
}

__global__ void cvt3_kernel(const float* __restrict__ w0, const float* __restrict__ w1,
                            const float* __restrict__ w2, ushort* __restrict__ out, int n) {
  const float* in = (blockIdx.y == 0) ? w0 : (blockIdx.y == 1) ? w1 : w2;
  ushort* o = out + (size_t)blockIdx.y * n;
  int idx = blockIdx.x * blockDim.x + threadIdx.x;
  int stride = gridDim.x * blockDim.x;
  for (long i = (long)idx * 8; i < n; i += (long)stride * 8) {
    const float4 f0 = *(const float4*)(in + i);
    const float4 f1 = *(const float4*)(in + i + 4);
    union { ushort u[8]; uint4 v; } r;
    r.u[0] = f2b(f0.x); r.u[1] = f2b(f0.y); r.u[2] = f2b(f0.z); r.u[3] = f2b(f0.w);
    r.u[4] = f2b(f1.x); r.u[5] = f2b(f1.y); r.u[6] = f2b(f1.z); r.u[7] = f2b(f1.w);
    *(uint4*)(o + i) = r.v;
  }
}

// K1: fused K/V GEMM + batch reduction, BATCH-PAIRED (LDS traffic cut).
// Block 256t x 64h, 8 waves (4t x 2h), wave tile 64t x 32h (m4 n2).
// Each phase = one BK=32 K-step for TWO batches: Wk/Wv fragments are
// b-invariant, so B-frags are read once (4 ds_read) and feed both batches'
// MFMAs (64 total); A-frags 8 reads (4 per batch). Reads/phase drop 16->12
// per 64 MFMA (LDS was the measured binder: 179KB/phase @85B/cyc ~= R10's
// 146us). acc doubles (accK/accV x2b = 128 VGPR), sums unchanged (64).
// Triple-buffered LDS (120 KiB), counted vmcnt(5), 1 barrier/phase.
// Swizzle both sides (4 chunks/row): chunk' = chunk ^ ((row>>1)&3).
// XCD swizzle: lid=(bid&7)*32+(bid>>3) -> each XCD = 2 t-panels x 16 h-panels.
__global__ __launch_bounds__(512, 2) void kv_kernel(
    const ushort* __restrict__ xb, const ushort* __restrict__ Wkb,
    const ushort* __restrict__ Wvb, const float* __restrict__ bk,
    const float* __restrict__ bv, const float* __restrict__ wbias,
    float* __restrict__ weighted) {
  extern __shared__ ushort lds[];
  ushort* const AsB = lds;           // 3 bufs x [2 b][256x32] = 3x16384 elems
  ushort* const BsB = lds + 49152;   // 3 bufs x [K|V][64x32]  = 3x4096 elems

  const int tid = threadIdx.x;
  const int lane = tid & 63;
  const int w = tid >> 6;       // 0..7
  const int wrow = w >> 1;      // 0..3  (64-row granule)
  const int wcol = w & 1;       // 0..1  (32-col granule)

  const int bid = blockIdx.x;               // 256 blocks
  const int lid = (bid & 7) * 32 + (bid >> 3);
  const int t0 = (lid >> 4) * 256;          // t-panel 0..15
  const int h0 = (lid & 15) * 64;           // h-panel 0..15

  // A staging: chunk j*512+tid (j=0,1 per b): row = tid>>2 (+128j), phys = tid&3,
  // source logical chunk = phys ^ ((row>>1)&3) = (tid&3) ^ ((tid>>3)&3).
  const int rA = tid >> 2;                        // 0..127
  const int lcA = (tid & 3) ^ ((tid >> 3) & 3);
  // B staging: ci = tid&255 over one 64x32 tile (K: tid<256, V: tid>=256).
  const int ci = tid & 255;
  const int rB = ci >> 2;                         // 0..63
  const int lcB = (ci & 3) ^ ((ci >> 3) & 3);

  const ushort* xsb = xb + (size_t)(t0 + rA) * D_ + lcA * 8;
  const ushort* wsrc = ((tid < 256) ? Wkb : Wvb) + (size_t)(h0 + rB) * D_ + lcB * 8;

  auto stage = [&](int p, int buf) {  // 5 loads/thread
    const int b0 = (p >> 5) * 2;
    const int kt = (p & 31) << 5;
    const ushort* x0 = xsb + (size_t)b0 * (T_ * D_) + kt;
    ushort* Ab = AsB + buf * 16384;
    GLOAD16(x0, Ab + tid * 8);
    GLOAD16(x0 + (size_t)128 * D_, Ab + (512 + tid) * 8);
    GLOAD16(x0 + (size_t)(T_ * D_), Ab + (1024 + tid) * 8);
    GLOAD16(x0 + (size_t)(T_ * D_ + 128 * D_), Ab + (1536 + tid) * 8);
    GLOAD16(wsrc + kt, BsB + buf * 4096 + tid * 8);
  };

  // fragment reads: row*32 + phys*8; phys = (lane>>4) ^ ((row>>1)&3);
  // (row>>1)&3 reduces to ((lane&15)>>1)&3 for both A and B (no carries).
  const int sw = ((lane & 15) >> 1) & 3;
  const int aBase = (wrow * 64 + (lane & 15)) * 32 + ((lane >> 4) ^ sw) * 8;  // +m*512, +b*8192
  const int bBase = (wcol * 32 + (lane & 15)) * 32 + ((lane >> 4) ^ sw) * 8;  // +n*512 (+2048 for V)

  float wbc[2], bkc[2], bvc[2];
#pragma unroll
  for (int n = 0; n < 2; ++n) {
    int h = h0 + wcol * 32 + n * 16 + (lane & 15);
    wbc[n] = wbias[h];
    bkc[n] = bk[h];
    bvc[n] = bv[h];
  }

  floatx4 accK[2][4][2] = {};
  floatx4 accV[2][4][2] = {};
  floatx4 sumN[4][2] = {};
  floatx4 sumWV[4][2] = {};

  stage(0, 0);
  stage(1, 1);
  asm volatile("s_waitcnt vmcnt(5)" ::: "memory");  // stage(0) landed
  __builtin_amdgcn_s_barrier();

  int cur = 0, stg = 2;
  for (int p = 0; p < 128; ++p) {  // 4 b-pairs x 32 K-steps
    if (p < 126) stage(p + 2, stg);

    const ushort* Ab = AsB + cur * 16384;
    const ushort* Bb = BsB + cur * 4096;
    short8 kf[2], vf[2], af[4];
    kf[0] = *(const short8*)(Bb + bBase);
    kf[1] = *(const short8*)(Bb + bBase + 512);
    vf[0] = *(const short8*)(Bb + 2048 + bBase);
    vf[1] = *(const short8*)(Bb + 2048 + bBase + 512);
#pragma unroll
    for (int bb = 0; bb < 2; ++bb) {
#pragma unroll
      for (int m = 0; m < 4; ++m)
        af[m] = *(const short8*)(Ab + bb * 8192 + aBase + m * 512);
      __builtin_amdgcn_s_setprio(1);
#pragma unroll
      for (int m = 0; m < 4; ++m)
#pragma unroll
        for (int n = 0; n < 2; ++n) {
          accK[bb][m][n] = __builtin_amdgcn_mfma_f32_16x16x32_bf16(af[m], kf[n], accK[bb][m][n], 0, 0, 0);
          accV[bb][m][n] = __builtin_amdgcn_mfma_f32_16x16x32_bf16(af[m], vf[n], accV[bb][m][n], 0, 0, 0);
        }
      __builtin_amdgcn_s_setprio(0);
    }

    if ((p & 31) == 31) {  // pair complete: fold exp-weighted sums, reset acc
#pragma unroll
      for (int bb = 0; bb < 2; ++bb)
#pragma unroll
        for (int m = 0; m < 4; ++m)
#pragma unroll
          for (int n = 0; n < 2; ++n) {
#pragma unroll
            for (int r = 0; r < 4; ++r) {
              float nmr = __expf(accK[bb][m][n][r] + bkc[n] + wbc[n]);
              sumN[m][n][r] += nmr;
              sumWV[m][n][r] += nmr * (accV[bb][m][n][r] + bvc[n]);
            }
            accK[bb][m][n] = floatx4{0.f, 0.f, 0.f, 0.f};
            accV[bb][m][n] = floatx4{0.f, 0.f, 0.f, 0.f};
          }
    }

    if (p < 126) { asm volatile("s_waitcnt vmcnt(5)" ::: "memory"); }
    else         { asm volatile("s_waitcnt vmcnt(0)" ::: "memory"); }
    __builtin_amdgcn_s_barrier();
    cur = (cur == 2) ? 0 : cur + 1;
    stg = (stg == 2) ? 0 : stg + 1;
  }

  // C/D layout: col = lane&15, row = (lane>>4)*4 + r
#pragma unroll
  for (int m = 0; m < 4; ++m)
#pragma unroll
    for (int n = 0; n < 2; ++n)
#pragma unroll
      for (int r = 0; r < 4; ++r) {
        int t = t0 + wrow * 64 + m * 16 + (lane >> 4) * 4 + r;
        int h = h0 + wcol * 32 + n * 16 + (lane & 15);
        weighted[(size_t)t * H_ + h] = sumWV[m][n][r] / sumN[m][n][r];
      }
}

// K2: Q GEMM + sigmoid(Q)*weighted epilogue (R10, passed @~99us).
__global__ __launch_bounds__(512, 2) void q_kernel(
    const ushort* __restrict__ Am, const ushort* __restrict__ Bm,
    const float* __restrict__ bq, const float* __restrict__ weighted,
    float* __restrict__ out) {
  extern __shared__ ushort lds[];

  const int tid = threadIdx.x;
  const int lane = tid & 63;
  const int w = tid >> 6;     // 0..7
  const int wr = w >> 2;      // 0..1  (128-row granule)
  const int wc = w & 3;       // 0..3  (64-col granule)

  const int bid = blockIdx.x;               // 512 blocks
  const int lid = (bid & 7) * 64 + (bid >> 3);
  const int R0 = (lid >> 2) * 256;          // row-panel 0..127
  const int C0 = (lid & 3) * 256;           // col-panel 0..3

  const int r0 = tid >> 2;                       // 0..127
  const int lc = (tid & 3) ^ ((tid >> 3) & 3);
  const ushort* asrc = Am + (size_t)(R0 + r0) * D_ + lc * 8;
  const ushort* bsrc = Bm + (size_t)(C0 + r0) * D_ + lc * 8;

  auto stage = [&](int t) {  // 4 gloads/thread
    const int nb = t & 3;
    const int kt = t * 32;
    GLOAD16(asrc + kt, lds + nb * 8192 + tid * 8);
    GLOAD16(asrc + kt + (size_t)128 * D_, lds + nb * 8192 + (512 + tid) * 8);
    GLOAD16(bsrc + kt, lds + 32768 + nb * 8192 + tid * 8);
    GLOAD16(bsrc + kt + (size_t)128 * D_, lds + 32768 + nb * 8192 + (512 + tid) * 8);
  };

  const int baseA = wr * 128 + (lane & 15);
  const int baseB = wc * 64 + (lane & 15);
  const int aOff = baseA * 32 + ((lane >> 4) ^ ((baseA >> 1) & 3)) * 8;
  const int bOff = baseB * 32 + ((lane >> 4) ^ ((baseB >> 1) & 3)) * 8;

  floatx4 acc[8][4] = {};

  stage(0); stage(1);
  asm volatile("s_waitcnt vmcnt(4)" ::: "memory");  // tile 0 landed
  __builtin_amdgcn_s_barrier();

  const int NT = D_ / 32;  // 32
  for (int t = 0; t < NT; ++t) {
    if (t < NT - 2) stage(t + 2);
    const ushort* Ab = lds + (t & 3) * 8192;
    const ushort* Bb = lds + 32768 + (t & 3) * 8192;

    short8 b[4], a[8];
#pragma unroll
    for (int n = 0; n < 4; ++n) b[n] = *(const short8*)(Bb + bOff + n * 512);
#pragma unroll
    for (int m = 0; m < 8; ++m) a[m] = *(const short8*)(Ab + aOff + m * 512);
#pragma unroll
    for (int m = 0; m < 8; ++m)
#pragma unroll
      for (int n = 0; n < 4; ++n)
        acc[m][n] = __builtin_amdgcn_mfma_f32_16x16x32_bf16(a[m], b[n], acc[m][n], 0, 0, 0);

    if (t < NT - 2) { asm volatile("s_waitcnt vmcnt(4)" ::: "memory"); }
    else            { asm volatile("s_waitcnt vmcnt(0)" ::: "memory"); }
    __builtin_amdgcn_s_barrier();
  }

  // ---- epilogue: in-LDS transpose, 2 m-halves, coalesced stores ----
  const int lrb = wr * 64 + (lane >> 4) * 4;  // + mi*16 + r  (0..127)
  const int lcol = wc * 64 + (lane & 15);     // + n*16
#pragma unroll
  for (int mh = 0; mh < 2; ++mh) {
    if (mh) __builtin_amdgcn_s_barrier();
    float* lf = (float*)lds;  // 128 x 256 fp32 = 128 KiB
#pragma unroll
    for (int mi = 0; mi < 4; ++mi)
#pragma unroll
      for (int n = 0; n < 4; ++n)
#pragma unroll
        for (int r = 0; r < 4; ++r)
          lf[(lrb + mi * 16 + r) * 256 + lcol + n * 16] = acc[mh * 4 + mi][n][r];
    __builtin_amdgcn_s_barrier();
#pragma unroll
    for (int j = 0; j < 16; ++j) {
      int cidx = j * 512 + tid;    // 0..8191 float4 chunks
      int lr = cidx >> 6;
      int cc = cidx & 63;
      int grow = R0 + (lr >> 6) * 128 + mh * 64 + (lr & 63);
      float4 v = *(float4*)(lf + lr * 256 + cc * 4);
      float4 bq4 = *(const float4*)(bq + C0 + cc * 4);
      float4 wv = *(const float4*)(weighted + (size_t)(grow & (T_ - 1)) * H_ + C0 + cc * 4);
      float4 o;
      o.x = wv.x / (1.f + __expf(-(v.x + bq4.x)));
      o.y = wv.y / (1.f + __expf(-(v.y + bq4.y)));
      o.z = wv.z / (1.f + __expf(-(v.z + bq4.z)));
      o.w = wv.w / (1.f + __expf(-(v.w + bq4.w)));
      *(float4*)(out + (size_t)grow * H_ + C0 + cc * 4) = o;
    }
  }
}

extern "C" void kernel_launch(void* const* d_in, const int* in_sizes, int n_in,
                              void* d_out, int out_size, void* d_ws, size_t ws_size,
                              hipStream_t stream) {
  (void)in_sizes; (void)n_in; (void)out_size; (void)ws_size;
  const float* x = (const float*)d_in[0];
  const float* Wq = (const float*)d_in[1];
  const float* bq = (const float*)d_in[2];
  const float* Wk = (const float*)d_in[3];
  const float* bk = (const float*)d_in[4];
  const float* Wv = (const float*)d_in[5];
  const float* bv = (const float*)d_in[6];
  const float* wbias = (const float*)d_in[7];
  float* out = (float*)d_out;

  char* ws = (char*)d_ws;
  const size_t XN = (size_t)B_ * T_ * D_;   // 33,554,432
  const size_t WN = (size_t)H_ * D_;        // 1,048,576
  ushort* xb  = (ushort*)ws;                             // 64 MiB
  ushort* Wqb = (ushort*)(ws + XN * 2);                  // 2 MiB
  ushort* Wkb = Wqb + WN;                                // 2 MiB
  ushort* Wvb = Wkb + WN;                                // 2 MiB
  float* weighted = (float*)(ws + XN * 2 + 3 * WN * 2);  // 16 MiB

  (void)hipFuncSetAttribute((const void*)kv_kernel,
                            hipFuncAttributeMaxDynamicSharedMemorySize, 122880);
  (void)hipFuncSetAttribute((const void*)q_kernel,
                            hipFuncAttributeMaxDynamicSharedMemorySize, 131072);

  cvt_kernel<<<2048, 256, 0, stream>>>(x, xb, (int)XN);
  cvt3_kernel<<<dim3(512, 3), 256, 0, stream>>>(Wq, Wk, Wv, Wqb, (int)WN);

  kv_kernel<<<256, 512, 122880, stream>>>(xb, Wkb, Wvb, bk, bv, wbias, weighted);
  q_kernel<<<512, 512, 131072, stream>>>(xb, Wqb, bq, weighted, out);
}